// Round 3
// baseline (278.162 us; speedup 1.0000x reference)
//
#include <hip/hip_runtime.h>
#include <math.h>

#define BLOCK 256
#define GRID 2048
#define UNROLL 4

// Stage 1: grid-stride float4 loads, unrolled x4 with stride-separated
// indices -> 8 independent 16B loads in flight per thread before any
// dependent use (latency hiding via ILP; TLP is already at the 8192-wave
// device capacity). Four accumulators break the FMA dependency chain.
__global__ __launch_bounds__(BLOCK) void partial_sq_sum(
    const float4* __restrict__ a, const float4* __restrict__ b,
    float* __restrict__ partial, int n4) {
    int tid = blockIdx.x * BLOCK + threadIdx.x;
    int stride = GRID * BLOCK;
    float acc0 = 0.0f, acc1 = 0.0f, acc2 = 0.0f, acc3 = 0.0f;
    int i = tid;
    for (; i + 3 * stride < n4; i += UNROLL * stride) {
        float4 x0 = a[i];
        float4 x1 = a[i + stride];
        float4 x2 = a[i + 2 * stride];
        float4 x3 = a[i + 3 * stride];
        float4 y0 = b[i];
        float4 y1 = b[i + stride];
        float4 y2 = b[i + 2 * stride];
        float4 y3 = b[i + 3 * stride];
        float d;
        d = x0.x - y0.x; acc0 += d * d;
        d = x0.y - y0.y; acc0 += d * d;
        d = x0.z - y0.z; acc0 += d * d;
        d = x0.w - y0.w; acc0 += d * d;
        d = x1.x - y1.x; acc1 += d * d;
        d = x1.y - y1.y; acc1 += d * d;
        d = x1.z - y1.z; acc1 += d * d;
        d = x1.w - y1.w; acc1 += d * d;
        d = x2.x - y2.x; acc2 += d * d;
        d = x2.y - y2.y; acc2 += d * d;
        d = x2.z - y2.z; acc2 += d * d;
        d = x2.w - y2.w; acc2 += d * d;
        d = x3.x - y3.x; acc3 += d * d;
        d = x3.y - y3.y; acc3 += d * d;
        d = x3.z - y3.z; acc3 += d * d;
        d = x3.w - y3.w; acc3 += d * d;
    }
    // tail (not taken for N=32M with this grid, but keep it correct)
    for (; i < n4; i += stride) {
        float4 x = a[i];
        float4 y = b[i];
        float d;
        d = x.x - y.x; acc0 += d * d;
        d = x.y - y.y; acc0 += d * d;
        d = x.z - y.z; acc0 += d * d;
        d = x.w - y.w; acc0 += d * d;
    }
    float acc = (acc0 + acc1) + (acc2 + acc3);
    // wave-64 reduction
    #pragma unroll
    for (int off = 32; off > 0; off >>= 1)
        acc += __shfl_down(acc, off, 64);
    __shared__ float smem[BLOCK / 64];
    int lane = threadIdx.x & 63;
    int wave = threadIdx.x >> 6;
    if (lane == 0) smem[wave] = acc;
    __syncthreads();
    if (threadIdx.x == 0) {
        float s = 0.0f;
        #pragma unroll
        for (int w = 0; w < BLOCK / 64; ++w) s += smem[w];
        partial[blockIdx.x] = s;
    }
}

// Stage 2: one block sums the GRID partials, applies the exact-match
// element-0 correction ((0.8*d0)^2 - d0^2 iff d0 in {3,4,5,6}), divides by N.
__global__ __launch_bounds__(BLOCK) void finalize(
    const float* __restrict__ partial, int n_partial,
    const float* __restrict__ in0, const float* __restrict__ tg0,
    float* __restrict__ out, float inv_n) {
    float acc = 0.0f;
    for (int i = threadIdx.x; i < n_partial; i += BLOCK)
        acc += partial[i];
    #pragma unroll
    for (int off = 32; off > 0; off >>= 1)
        acc += __shfl_down(acc, off, 64);
    __shared__ float smem[BLOCK / 64];
    int lane = threadIdx.x & 63;
    int wave = threadIdx.x >> 6;
    if (lane == 0) smem[wave] = acc;
    __syncthreads();
    if (threadIdx.x == 0) {
        float s = 0.0f;
        #pragma unroll
        for (int w = 0; w < BLOCK / 64; ++w) s += smem[w];
        float d0 = fabsf(in0[0] - tg0[0]);
        if (d0 == 3.0f || d0 == 4.0f || d0 == 5.0f || d0 == 6.0f) {
            float d0s = 0.8f * d0;
            s += d0s * d0s - d0 * d0;
        }
        out[0] = s * inv_n;
    }
}

extern "C" void kernel_launch(void* const* d_in, const int* in_sizes, int n_in,
                              void* d_out, int out_size, void* d_ws, size_t ws_size,
                              hipStream_t stream) {
    const float* input  = (const float*)d_in[0];
    const float* target = (const float*)d_in[1];
    float* out = (float*)d_out;
    float* partial = (float*)d_ws;  // GRID floats of scratch

    int n = in_sizes[0];          // 33554432
    int n4 = n >> 2;              // float4 count (N divisible by 4)

    partial_sq_sum<<<GRID, BLOCK, 0, stream>>>(
        (const float4*)input, (const float4*)target, partial, n4);
    finalize<<<1, BLOCK, 0, stream>>>(
        partial, GRID, input, target, out, 1.0f / (float)n);
}

// Round 4
// 254.252 us; speedup vs baseline: 1.0940x; 1.0940x over previous
//
#include <hip/hip_runtime.h>
#include <math.h>

#define BLOCK 256
#define GRID 2048
#define UNROLL 4

typedef float vfloat4 __attribute__((ext_vector_type(4)));

// Stage 1: grid-stride float4 loads, x4 unrolled, NONTEMPORAL (nt) loads —
// inputs are streamed exactly once, so L2 allocation is pure overhead; nt
// bypasses cache retention and should lift the ~2.6 TB/s L2-fill cap.
__global__ __launch_bounds__(BLOCK) void partial_sq_sum(
    const vfloat4* __restrict__ a, const vfloat4* __restrict__ b,
    float* __restrict__ partial, int n4) {
    int tid = blockIdx.x * BLOCK + threadIdx.x;
    int stride = GRID * BLOCK;
    float acc0 = 0.0f, acc1 = 0.0f, acc2 = 0.0f, acc3 = 0.0f;
    int i = tid;
    for (; i + 3 * stride < n4; i += UNROLL * stride) {
        vfloat4 x0 = __builtin_nontemporal_load(a + i);
        vfloat4 x1 = __builtin_nontemporal_load(a + i + stride);
        vfloat4 x2 = __builtin_nontemporal_load(a + i + 2 * stride);
        vfloat4 x3 = __builtin_nontemporal_load(a + i + 3 * stride);
        vfloat4 y0 = __builtin_nontemporal_load(b + i);
        vfloat4 y1 = __builtin_nontemporal_load(b + i + stride);
        vfloat4 y2 = __builtin_nontemporal_load(b + i + 2 * stride);
        vfloat4 y3 = __builtin_nontemporal_load(b + i + 3 * stride);
        vfloat4 d0 = x0 - y0;
        vfloat4 d1 = x1 - y1;
        vfloat4 d2 = x2 - y2;
        vfloat4 d3 = x3 - y3;
        acc0 += d0.x * d0.x + d0.y * d0.y + d0.z * d0.z + d0.w * d0.w;
        acc1 += d1.x * d1.x + d1.y * d1.y + d1.z * d1.z + d1.w * d1.w;
        acc2 += d2.x * d2.x + d2.y * d2.y + d2.z * d2.z + d2.w * d2.w;
        acc3 += d3.x * d3.x + d3.y * d3.y + d3.z * d3.z + d3.w * d3.w;
    }
    // tail (not taken for N=32M with this grid, but keep it correct)
    for (; i < n4; i += stride) {
        vfloat4 x = __builtin_nontemporal_load(a + i);
        vfloat4 y = __builtin_nontemporal_load(b + i);
        vfloat4 d = x - y;
        acc0 += d.x * d.x + d.y * d.y + d.z * d.z + d.w * d.w;
    }
    float acc = (acc0 + acc1) + (acc2 + acc3);
    // wave-64 reduction
    #pragma unroll
    for (int off = 32; off > 0; off >>= 1)
        acc += __shfl_down(acc, off, 64);
    __shared__ float smem[BLOCK / 64];
    int lane = threadIdx.x & 63;
    int wave = threadIdx.x >> 6;
    if (lane == 0) smem[wave] = acc;
    __syncthreads();
    if (threadIdx.x == 0) {
        float s = 0.0f;
        #pragma unroll
        for (int w = 0; w < BLOCK / 64; ++w) s += smem[w];
        partial[blockIdx.x] = s;
    }
}

// Stage 2: one block sums the GRID partials, applies the exact-match
// element-0 correction ((0.8*d0)^2 - d0^2 iff d0 in {3,4,5,6}), divides by N.
__global__ __launch_bounds__(BLOCK) void finalize(
    const float* __restrict__ partial, int n_partial,
    const float* __restrict__ in0, const float* __restrict__ tg0,
    float* __restrict__ out, float inv_n) {
    float acc = 0.0f;
    for (int i = threadIdx.x; i < n_partial; i += BLOCK)
        acc += partial[i];
    #pragma unroll
    for (int off = 32; off > 0; off >>= 1)
        acc += __shfl_down(acc, off, 64);
    __shared__ float smem[BLOCK / 64];
    int lane = threadIdx.x & 63;
    int wave = threadIdx.x >> 6;
    if (lane == 0) smem[wave] = acc;
    __syncthreads();
    if (threadIdx.x == 0) {
        float s = 0.0f;
        #pragma unroll
        for (int w = 0; w < BLOCK / 64; ++w) s += smem[w];
        float d0 = fabsf(in0[0] - tg0[0]);
        if (d0 == 3.0f || d0 == 4.0f || d0 == 5.0f || d0 == 6.0f) {
            float d0s = 0.8f * d0;
            s += d0s * d0s - d0 * d0;
        }
        out[0] = s * inv_n;
    }
}

extern "C" void kernel_launch(void* const* d_in, const int* in_sizes, int n_in,
                              void* d_out, int out_size, void* d_ws, size_t ws_size,
                              hipStream_t stream) {
    const float* input  = (const float*)d_in[0];
    const float* target = (const float*)d_in[1];
    float* out = (float*)d_out;
    float* partial = (float*)d_ws;  // GRID floats of scratch

    int n = in_sizes[0];          // 33554432
    int n4 = n >> 2;              // float4 count (N divisible by 4)

    partial_sq_sum<<<GRID, BLOCK, 0, stream>>>(
        (const vfloat4*)input, (const vfloat4*)target, partial, n4);
    finalize<<<1, BLOCK, 0, stream>>>(
        partial, GRID, input, target, out, 1.0f / (float)n);
}

// Round 5
// 247.107 us; speedup vs baseline: 1.1257x; 1.0289x over previous
//
#include <hip/hip_runtime.h>
#include <math.h>

#define BLOCK 256
#define GRID 1024
#define UNROLL 4

typedef float vfloat4 __attribute__((ext_vector_type(4)));

// Stage 1: each block consumes a CONTIGUOUS 16 KB chunk per outer iteration
// (unroll segments 1 KB apart instead of 8 MB), halved grid -> 4x fewer
// concurrent DRAM streams. nt loads retained (no L2/L3 retention for
// streamed-once data). Discriminates inbound-cap vs locality theories.
__global__ __launch_bounds__(BLOCK) void partial_sq_sum(
    const vfloat4* __restrict__ a, const vfloat4* __restrict__ b,
    float* __restrict__ partial, int n4) {
    const int chunk = UNROLL * BLOCK;          // 1024 float4 = 16 KB per block-iter
    const int outer_stride = GRID * chunk;     // 1M float4 = 16 MB per grid-iter
    float acc0 = 0.0f, acc1 = 0.0f, acc2 = 0.0f, acc3 = 0.0f;
    for (int base = blockIdx.x * chunk + threadIdx.x; base + 3 * BLOCK < n4;
         base += outer_stride) {
        vfloat4 x0 = __builtin_nontemporal_load(a + base);
        vfloat4 x1 = __builtin_nontemporal_load(a + base + BLOCK);
        vfloat4 x2 = __builtin_nontemporal_load(a + base + 2 * BLOCK);
        vfloat4 x3 = __builtin_nontemporal_load(a + base + 3 * BLOCK);
        vfloat4 y0 = __builtin_nontemporal_load(b + base);
        vfloat4 y1 = __builtin_nontemporal_load(b + base + BLOCK);
        vfloat4 y2 = __builtin_nontemporal_load(b + base + 2 * BLOCK);
        vfloat4 y3 = __builtin_nontemporal_load(b + base + 3 * BLOCK);
        vfloat4 d0 = x0 - y0;
        vfloat4 d1 = x1 - y1;
        vfloat4 d2 = x2 - y2;
        vfloat4 d3 = x3 - y3;
        acc0 += d0.x * d0.x + d0.y * d0.y + d0.z * d0.z + d0.w * d0.w;
        acc1 += d1.x * d1.x + d1.y * d1.y + d1.z * d1.z + d1.w * d1.w;
        acc2 += d2.x * d2.x + d2.y * d2.y + d2.z * d2.z + d2.w * d2.w;
        acc3 += d3.x * d3.x + d3.y * d3.y + d3.z * d3.z + d3.w * d3.w;
    }
    // tail for n4 not divisible by GRID*UNROLL*BLOCK (not taken at N=32M)
    int done = (n4 / outer_stride) * outer_stride;
    for (int i = done + blockIdx.x * chunk + threadIdx.x; i < n4; i += BLOCK) {
        vfloat4 x = __builtin_nontemporal_load(a + i);
        vfloat4 y = __builtin_nontemporal_load(b + i);
        vfloat4 d = x - y;
        acc0 += d.x * d.x + d.y * d.y + d.z * d.z + d.w * d.w;
    }
    float acc = (acc0 + acc1) + (acc2 + acc3);
    // wave-64 reduction
    #pragma unroll
    for (int off = 32; off > 0; off >>= 1)
        acc += __shfl_down(acc, off, 64);
    __shared__ float smem[BLOCK / 64];
    int lane = threadIdx.x & 63;
    int wave = threadIdx.x >> 6;
    if (lane == 0) smem[wave] = acc;
    __syncthreads();
    if (threadIdx.x == 0) {
        float s = 0.0f;
        #pragma unroll
        for (int w = 0; w < BLOCK / 64; ++w) s += smem[w];
        partial[blockIdx.x] = s;
    }
}

// Stage 2: one block sums the GRID partials, applies the exact-match
// element-0 correction ((0.8*d0)^2 - d0^2 iff d0 in {3,4,5,6}), divides by N.
__global__ __launch_bounds__(BLOCK) void finalize(
    const float* __restrict__ partial, int n_partial,
    const float* __restrict__ in0, const float* __restrict__ tg0,
    float* __restrict__ out, float inv_n) {
    float acc = 0.0f;
    for (int i = threadIdx.x; i < n_partial; i += BLOCK)
        acc += partial[i];
    #pragma unroll
    for (int off = 32; off > 0; off >>= 1)
        acc += __shfl_down(acc, off, 64);
    __shared__ float smem[BLOCK / 64];
    int lane = threadIdx.x & 63;
    int wave = threadIdx.x >> 6;
    if (lane == 0) smem[wave] = acc;
    __syncthreads();
    if (threadIdx.x == 0) {
        float s = 0.0f;
        #pragma unroll
        for (int w = 0; w < BLOCK / 64; ++w) s += smem[w];
        float d0 = fabsf(in0[0] - tg0[0]);
        if (d0 == 3.0f || d0 == 4.0f || d0 == 5.0f || d0 == 6.0f) {
            float d0s = 0.8f * d0;
            s += d0s * d0s - d0 * d0;
        }
        out[0] = s * inv_n;
    }
}

extern "C" void kernel_launch(void* const* d_in, const int* in_sizes, int n_in,
                              void* d_out, int out_size, void* d_ws, size_t ws_size,
                              hipStream_t stream) {
    const float* input  = (const float*)d_in[0];
    const float* target = (const float*)d_in[1];
    float* out = (float*)d_out;
    float* partial = (float*)d_ws;  // GRID floats of scratch

    int n = in_sizes[0];          // 33554432
    int n4 = n >> 2;              // float4 count (N divisible by 4)

    partial_sq_sum<<<GRID, BLOCK, 0, stream>>>(
        (const vfloat4*)input, (const vfloat4*)target, partial, n4);
    finalize<<<1, BLOCK, 0, stream>>>(
        partial, GRID, input, target, out, 1.0f / (float)n);
}